// Round 1
// baseline (688.644 us; speedup 1.0000x reference)
//
#include <hip/hip_runtime.h>

// S5 associative scan: T=131072 timesteps, D=256 channels, fp32.
// combine(earlier=(Ai,Bi), later=(Aj,Bj)) = (Aj*Ai, Aj*Bi + Bj)
// 3-phase chunked scan: per-chunk aggregates -> scan aggregates -> apply.

#define T_TOTAL 131072
#define D_DIM   256
#define CHUNK   64                      // timesteps per block
#define NCHUNK  (T_TOTAL / CHUNK)       // 2048 blocks
#define NTHR    (D_DIM / 4)             // 64 threads, 4 channels each (float4)

// Pass 1: each block computes its chunk's aggregate (a = prod A, b = scan of Bu).
__global__ __launch_bounds__(NTHR) void s5_pass1(
    const float* __restrict__ A, const float* __restrict__ Bu,
    float* __restrict__ aggA, float* __restrict__ aggB)
{
    const int c  = blockIdx.x;
    const int ch = threadIdx.x * 4;
    const size_t base = (size_t)c * CHUNK * D_DIM + ch;

    float4 a = make_float4(1.f, 1.f, 1.f, 1.f);
    float4 b = make_float4(0.f, 0.f, 0.f, 0.f);

    #pragma unroll 4
    for (int t = 0; t < CHUNK; ++t) {
        const float4 at = *(const float4*)(A  + base + (size_t)t * D_DIM);
        const float4 bt = *(const float4*)(Bu + base + (size_t)t * D_DIM);
        a.x = at.x * a.x;  b.x = fmaf(at.x, b.x, bt.x);
        a.y = at.y * a.y;  b.y = fmaf(at.y, b.y, bt.y);
        a.z = at.z * a.z;  b.z = fmaf(at.z, b.z, bt.z);
        a.w = at.w * a.w;  b.w = fmaf(at.w, b.w, bt.w);
    }
    *(float4*)(aggA + (size_t)c * D_DIM + ch) = a;
    *(float4*)(aggB + (size_t)c * D_DIM + ch) = b;
}

// Pass 2: single block scans chunk aggregates -> exclusive prefixes per chunk.
__global__ __launch_bounds__(NTHR) void s5_pass2(
    const float* __restrict__ aggA, const float* __restrict__ aggB,
    float* __restrict__ preA, float* __restrict__ preB)
{
    const int ch = threadIdx.x * 4;
    float4 ra = make_float4(1.f, 1.f, 1.f, 1.f);
    float4 rb = make_float4(0.f, 0.f, 0.f, 0.f);

    for (int c = 0; c < NCHUNK; ++c) {
        const size_t o = (size_t)c * D_DIM + ch;
        *(float4*)(preA + o) = ra;
        *(float4*)(preB + o) = rb;
        const float4 ga = *(const float4*)(aggA + o);
        const float4 gb = *(const float4*)(aggB + o);
        // running = combine(running, agg)
        rb.x = fmaf(ga.x, rb.x, gb.x);  ra.x = ga.x * ra.x;
        rb.y = fmaf(ga.y, rb.y, gb.y);  ra.y = ga.y * ra.y;
        rb.z = fmaf(ga.z, rb.z, gb.z);  ra.z = ga.z * ra.z;
        rb.w = fmaf(ga.w, rb.w, gb.w);  ra.w = ga.w * ra.w;
    }
}

// Pass 3: re-read inputs, apply exclusive prefix, write both outputs.
__global__ __launch_bounds__(NTHR) void s5_pass3(
    const float* __restrict__ A, const float* __restrict__ Bu,
    const float* __restrict__ preA, const float* __restrict__ preB,
    float* __restrict__ outA, float* __restrict__ outB)
{
    const int c  = blockIdx.x;
    const int ch = threadIdx.x * 4;
    const size_t po = (size_t)c * D_DIM + ch;

    float4 ra = *(const float4*)(preA + po);
    float4 rb = *(const float4*)(preB + po);

    const size_t base = (size_t)c * CHUNK * D_DIM + ch;

    #pragma unroll 4
    for (int t = 0; t < CHUNK; ++t) {
        const size_t o = base + (size_t)t * D_DIM;
        const float4 at = *(const float4*)(A  + o);
        const float4 bt = *(const float4*)(Bu + o);
        rb.x = fmaf(at.x, rb.x, bt.x);  ra.x = at.x * ra.x;
        rb.y = fmaf(at.y, rb.y, bt.y);  ra.y = at.y * ra.y;
        rb.z = fmaf(at.z, rb.z, bt.z);  ra.z = at.z * ra.z;
        rb.w = fmaf(at.w, rb.w, bt.w);  ra.w = at.w * ra.w;
        *(float4*)(outA + o) = ra;
        *(float4*)(outB + o) = rb;
    }
}

extern "C" void kernel_launch(void* const* d_in, const int* in_sizes, int n_in,
                              void* d_out, int out_size, void* d_ws, size_t ws_size,
                              hipStream_t stream)
{
    const float* A  = (const float*)d_in[0];
    const float* Bu = (const float*)d_in[1];
    float* outA = (float*)d_out;                          // first T*D: A-scan
    float* outB = (float*)d_out + (size_t)T_TOTAL * D_DIM; // second T*D: Bu-scan

    // workspace: 4 arrays of NCHUNK*D floats (2 MB each, 8 MB total)
    float* aggA = (float*)d_ws;
    float* aggB = aggA + (size_t)NCHUNK * D_DIM;
    float* preA = aggB + (size_t)NCHUNK * D_DIM;
    float* preB = preA + (size_t)NCHUNK * D_DIM;

    s5_pass1<<<NCHUNK, NTHR, 0, stream>>>(A, Bu, aggA, aggB);
    s5_pass2<<<1, NTHR, 0, stream>>>(aggA, aggB, preA, preB);
    s5_pass3<<<NCHUNK, NTHR, 0, stream>>>(A, Bu, preA, preB, outA, outB);
}

// Round 3
// 497.038 us; speedup vs baseline: 1.3855x; 1.3855x over previous
//
#include <hip/hip_runtime.h>

// S5 associative scan: T=131072 timesteps, D=256 channels, fp32.
// combine(earlier=(Ai,Bi), later=(Aj,Bj)) = (Aj*Ai, Aj*Bi + Bj)
// 4-kernel hierarchical scan:
//   pass1 : 4096 blocks, per-chunk (32 steps) aggregate -> agg arrays
//   pass2a: 64 blocks, scan 64 chunk-aggs each -> in-place rel-prefix + super-agg
//   pass2b: 1 block, scan 64 super-aggs -> in-place super-prefix
//   pass3 : 4096 blocks, prefix = combine(superPre, rel), apply + write outputs

#define T_TOTAL 131072
#define D_DIM   256
#define CHUNK   32
#define NCHUNK  (T_TOTAL / CHUNK)      // 4096
#define NSUPER  64
#define SLEN    (NCHUNK / NSUPER)      // 64 chunks per superchunk
#define NTHR    (D_DIM / 4)            // 64 threads, 4 channels each (float4)

typedef float vfloat4 __attribute__((ext_vector_type(4)));  // native vec for NT stores

__device__ __forceinline__ void combine(float4& ra, float4& rb,
                                        const float4 ga, const float4 gb) {
    // (ra,rb) = combine(earlier=(ra,rb), later=(ga,gb))
    rb.x = fmaf(ga.x, rb.x, gb.x);  ra.x = ga.x * ra.x;
    rb.y = fmaf(ga.y, rb.y, gb.y);  ra.y = ga.y * ra.y;
    rb.z = fmaf(ga.z, rb.z, gb.z);  ra.z = ga.z * ra.z;
    rb.w = fmaf(ga.w, rb.w, gb.w);  ra.w = ga.w * ra.w;
}

__device__ __forceinline__ void nt_store4(float* p, const float4 v) {
    vfloat4 t = {v.x, v.y, v.z, v.w};
    __builtin_nontemporal_store(t, (vfloat4*)p);
}

// Pass 1: per-chunk aggregate.
__global__ __launch_bounds__(NTHR) void s5_pass1(
    const float* __restrict__ A, const float* __restrict__ Bu,
    float* __restrict__ aggA, float* __restrict__ aggB)
{
    const int c  = blockIdx.x;
    const int ch = threadIdx.x * 4;
    const size_t base = (size_t)c * CHUNK * D_DIM + ch;

    float4 a = make_float4(1.f, 1.f, 1.f, 1.f);
    float4 b = make_float4(0.f, 0.f, 0.f, 0.f);

    #pragma unroll 8
    for (int t = 0; t < CHUNK; ++t) {
        const float4 at = *(const float4*)(A  + base + (size_t)t * D_DIM);
        const float4 bt = *(const float4*)(Bu + base + (size_t)t * D_DIM);
        combine(a, b, at, bt);
    }
    *(float4*)(aggA + (size_t)c * D_DIM + ch) = a;
    *(float4*)(aggB + (size_t)c * D_DIM + ch) = b;
}

// Pass 2a: each block scans SLEN chunk-aggregates; in-place exclusive
// (relative) prefixes, plus one super-aggregate per block.
__global__ __launch_bounds__(NTHR) void s5_pass2a(
    float* __restrict__ aggA, float* __restrict__ aggB,
    float* __restrict__ supA, float* __restrict__ supB)
{
    const int s  = blockIdx.x;
    const int ch = threadIdx.x * 4;

    float4 ra = make_float4(1.f, 1.f, 1.f, 1.f);
    float4 rb = make_float4(0.f, 0.f, 0.f, 0.f);

    for (int i = 0; i < SLEN; ++i) {
        const size_t o = (size_t)(s * SLEN + i) * D_DIM + ch;
        const float4 ga = *(const float4*)(aggA + o);
        const float4 gb = *(const float4*)(aggB + o);
        *(float4*)(aggA + o) = ra;   // becomes rel-exclusive prefix
        *(float4*)(aggB + o) = rb;
        combine(ra, rb, ga, gb);
    }
    *(float4*)(supA + (size_t)s * D_DIM + ch) = ra;
    *(float4*)(supB + (size_t)s * D_DIM + ch) = rb;
}

// Pass 2b: one block scans the NSUPER super-aggregates in-place -> exclusive.
__global__ __launch_bounds__(NTHR) void s5_pass2b(
    float* __restrict__ supA, float* __restrict__ supB)
{
    const int ch = threadIdx.x * 4;
    float4 ra = make_float4(1.f, 1.f, 1.f, 1.f);
    float4 rb = make_float4(0.f, 0.f, 0.f, 0.f);

    for (int s = 0; s < NSUPER; ++s) {
        const size_t o = (size_t)s * D_DIM + ch;
        const float4 ga = *(const float4*)(supA + o);
        const float4 gb = *(const float4*)(supB + o);
        *(float4*)(supA + o) = ra;
        *(float4*)(supB + o) = rb;
        combine(ra, rb, ga, gb);
    }
}

// Pass 3: prefix = combine(superPre, rel); re-read inputs, apply, write.
__global__ __launch_bounds__(NTHR) void s5_pass3(
    const float* __restrict__ A, const float* __restrict__ Bu,
    const float* __restrict__ relA, const float* __restrict__ relB,
    const float* __restrict__ supA, const float* __restrict__ supB,
    float* __restrict__ outA, float* __restrict__ outB)
{
    const int c  = blockIdx.x;
    const int ch = threadIdx.x * 4;
    const int s  = c / SLEN;

    const size_t co = (size_t)c * D_DIM + ch;
    const size_t so = (size_t)s * D_DIM + ch;

    const float4 rA = *(const float4*)(relA + co);
    const float4 rB = *(const float4*)(relB + co);
    const float4 sA = *(const float4*)(supA + so);
    const float4 sB = *(const float4*)(supB + so);

    // exclusive prefix for this chunk = combine(earlier=sup, later=rel)
    float4 ra, rb;
    rb.x = fmaf(rA.x, sB.x, rB.x);  ra.x = rA.x * sA.x;
    rb.y = fmaf(rA.y, sB.y, rB.y);  ra.y = rA.y * sA.y;
    rb.z = fmaf(rA.z, sB.z, rB.z);  ra.z = rA.z * sA.z;
    rb.w = fmaf(rA.w, sB.w, rB.w);  ra.w = rA.w * sA.w;

    const size_t base = (size_t)c * CHUNK * D_DIM + ch;

    #pragma unroll 8
    for (int t = 0; t < CHUNK; ++t) {
        const size_t o = base + (size_t)t * D_DIM;
        const float4 at = *(const float4*)(A  + o);
        const float4 bt = *(const float4*)(Bu + o);
        combine(ra, rb, at, bt);
        nt_store4(outA + o, ra);
        nt_store4(outB + o, rb);
    }
}

extern "C" void kernel_launch(void* const* d_in, const int* in_sizes, int n_in,
                              void* d_out, int out_size, void* d_ws, size_t ws_size,
                              hipStream_t stream)
{
    const float* A  = (const float*)d_in[0];
    const float* Bu = (const float*)d_in[1];
    float* outA = (float*)d_out;
    float* outB = (float*)d_out + (size_t)T_TOTAL * D_DIM;

    // workspace: aggA/aggB (4 MB each), supA/supB (64 KB each)
    float* aggA = (float*)d_ws;
    float* aggB = aggA + (size_t)NCHUNK * D_DIM;
    float* supA = aggB + (size_t)NCHUNK * D_DIM;
    float* supB = supA + (size_t)NSUPER * D_DIM;

    s5_pass1 <<<NCHUNK, NTHR, 0, stream>>>(A, Bu, aggA, aggB);
    s5_pass2a<<<NSUPER, NTHR, 0, stream>>>(aggA, aggB, supA, supB);
    s5_pass2b<<<1,      NTHR, 0, stream>>>(supA, supB);
    s5_pass3 <<<NCHUNK, NTHR, 0, stream>>>(A, Bu, aggA, aggB, supA, supB, outA, outB);
}